// Round 1
// baseline (1252.994 us; speedup 1.0000x reference)
//
#include <hip/hip_runtime.h>
#include <hip/hip_bf16.h>
#include <math.h>

// Problem constants (N_WAY=64, K_SHOT=5, Q_QUERY=128, D_FEAT=128)
#define M     8192      // n*q query rows
#define D     128       // feature dim
#define NCLS  64        // n classes
#define KSHOT 5
#define XROW  133       // (k+q) rows per class in x
#define KTOP  9
#define EPSV  1e-8f

// k2 config: 64 rows/block (one per lane), 8 waves, 4 j-splits
#define IB    64
#define W2    8
#define TPB2  (W2 * 64)
#define SJ    4
#define JPB   (M / SJ)      // 2048 columns per block
#define JPW   (JPB / W2)    // 256 columns per wave
#define NPART (SJ * W2)     // 32 partial top-9 lists per row

// ---------------------------------------------------------------------------
// register-resident top-9 with (value desc, index asc) tie-break, matching
// jax.lax.top_k semantics. Fully unrolled -> static indexing -> stays in VGPRs.
__device__ __forceinline__ void top9_insert(float (&kv)[KTOP], int (&ki)[KTOP],
                                            float v, int j) {
  // early-out: reject vs current 9th (common case: 1 compare)
  if (v > kv[KTOP - 1] || (v == kv[KTOP - 1] && j < ki[KTOP - 1])) {
    float cv = v; int cj = j;
#pragma unroll
    for (int t = 0; t < KTOP; ++t) {
      bool b = (cv > kv[t]) || (cv == kv[t] && cj < ki[t]);
      float tv = kv[t]; int ti = ki[t];
      kv[t] = b ? cv : tv;  ki[t] = b ? cj : ti;
      cv   = b ? tv : cv;   cj   = b ? ti : cj;
    }
  }
}

// ---------------------------------------------------------------------------
// k0: class prototypes = mean of 5 support rows, L2-normalized, stored
// TRANSPOSED protnT[d][c] so k3's per-lane-class reads are coalesced.
__global__ void k0_proto(const float* __restrict__ x, float* __restrict__ protnT) {
  int c = blockIdx.x;           // class 0..63
  int lane = threadIdx.x;       // 0..63 ; lane owns dims d=lane and d=lane+64
  const float* base = x + (size_t)(c * XROW) * D;
  float a0 = 0.f, a1 = 0.f;
#pragma unroll
  for (int s = 0; s < KSHOT; ++s) {
    a0 += base[s * D + lane];
    a1 += base[s * D + 64 + lane];
  }
  a0 *= 0.2f; a1 *= 0.2f;
  float ss = a0 * a0 + a1 * a1;
#pragma unroll
  for (int off = 1; off < 64; off <<= 1) ss += __shfl_xor(ss, off);
  float rn = 1.0f / fmaxf(sqrtf(ss), EPSV);
  protnT[lane * NCLS + c]        = a0 * rn;
  protnT[(lane + 64) * NCLS + c] = a1 * rn;
}

// ---------------------------------------------------------------------------
// k1: L2-normalize the 8192 query rows into qn (row-major, 4 MB).
__global__ void k1_qnorm(const float* __restrict__ x, float* __restrict__ qn) {
  int lane = threadIdx.x & 63;
  int wv = threadIdx.x >> 6;
  int r = blockIdx.x * 4 + wv;              // query row 0..8191
  int xr = (r >> 7) * XROW + KSHOT + (r & 127);
  const float* src = x + (size_t)xr * D;
  float v0 = src[lane], v1 = src[64 + lane];
  float ss = v0 * v0 + v1 * v1;
#pragma unroll
  for (int off = 1; off < 64; off <<= 1) ss += __shfl_xor(ss, off);
  float rn = 1.0f / fmaxf(sqrtf(ss), EPSV);
  qn[(size_t)r * D + lane]      = v0 * rn;
  qn[(size_t)r * D + 64 + lane] = v1 * rn;
}

// ---------------------------------------------------------------------------
// k2: the heavy pass. Block = 512 thr (8 waves), 64 rows (one per LANE).
// Row fragments live in LDS (XOR-swizzled so ds_read_b128 at fixed chunk is
// bank-conflict-free). Each wave streams its disjoint 256-column j-range;
// qn[j] is wave-uniform -> s_load -> SGPR operand of v_fmac. Per-lane
// register top-9; partial lists written to global for the merge kernel.
__global__ __launch_bounds__(TPB2) void
k2_topk(const float* __restrict__ qn, float* __restrict__ pkv, int* __restrict__ pki) {
  __shared__ float4 tile[IB * 32];          // 64 rows x 128 f32, swizzled: 32 KB

  int tid  = threadIdx.x;
  int lane = tid & 63;
  int wv   = __builtin_amdgcn_readfirstlane(tid >> 6);   // provably uniform
  int ib   = blockIdx.x >> 2;               // 128 i-blocks
  int js   = blockIdx.x & (SJ - 1);         // 4 j-splits
  int ibase = ib * IB;

  // stage this block's 64 qn rows, chunk-swizzled: slot = c ^ (row&7)
#pragma unroll
  for (int k = 0; k < (IB * 32) / TPB2; ++k) {   // 4 iterations
    int ch = k * TPB2 + tid;
    int row = ch >> 5, c = ch & 31;
    float4 v = *(const float4*)(qn + (size_t)(ibase + row) * D + c * 4);
    tile[row * 32 + (c ^ (row & 7))] = v;
  }
  __syncthreads();

  const int lane7 = lane & 7;
  const float4* tl = tile + lane * 32;

  float kv[KTOP]; int ki[KTOP];
#pragma unroll
  for (int t = 0; t < KTOP; ++t) { kv[t] = -INFINITY; ki[t] = 0x7fffffff; }

  const int j0 = js * JPB + wv * JPW;
  for (int jq = 0; jq < JPW; jq += 4) {
    int j = j0 + jq;
    const float4* b0 = (const float4*)(qn + (size_t)j * D);  // wave-uniform
    const float4* b1 = b0 + 32;
    const float4* b2 = b0 + 64;
    const float4* b3 = b0 + 96;
    float acc0 = 0.f, acc1 = 0.f, acc2 = 0.f, acc3 = 0.f;
#pragma unroll
    for (int c8 = 0; c8 < 32; c8 += 8) {
#pragma unroll
      for (int k = 0; k < 8; ++k) {
        int ci = c8 + k;
        // (c8+k)^lane7 == c8 + (k^lane7): c8 is 8-aligned, k,lane7 < 8
        float4 a = tl[c8 + (k ^ lane7)];
        float4 q0 = b0[ci], q1 = b1[ci], q2 = b2[ci], q3 = b3[ci];
        acc0 += a.x * q0.x + a.y * q0.y + a.z * q0.z + a.w * q0.w;
        acc1 += a.x * q1.x + a.y * q1.y + a.z * q1.z + a.w * q1.w;
        acc2 += a.x * q2.x + a.y * q2.y + a.z * q2.z + a.w * q2.w;
        acc3 += a.x * q3.x + a.y * q3.y + a.z * q3.z + a.w * q3.w;
      }
    }
    top9_insert(kv, ki, acc0, j);
    top9_insert(kv, ki, acc1, j + 1);
    top9_insert(kv, ki, acc2, j + 2);
    top9_insert(kv, ki, acc3, j + 3);
  }

  int i = ibase + lane;
  int p = js * W2 + wv;
  size_t base = ((size_t)i * NPART + p) * KTOP;
#pragma unroll
  for (int t = 0; t < KTOP; ++t) { pkv[base + t] = kv[t]; pki[base + t] = ki[t]; }
}

// ---------------------------------------------------------------------------
// k_merge: per row, merge the 32 partial top-9 lists (disjoint j-ranges).
__global__ void k_merge(const float* __restrict__ pkv, const int* __restrict__ pki,
                        float* __restrict__ kval, int* __restrict__ kidx) {
  int i = blockIdx.x * blockDim.x + threadIdx.x;   // 0..8191
  float kv[KTOP]; int ki[KTOP];
#pragma unroll
  for (int t = 0; t < KTOP; ++t) { kv[t] = -INFINITY; ki[t] = 0x7fffffff; }
  const float* pv = pkv + (size_t)i * NPART * KTOP;
  const int*   pi = pki + (size_t)i * NPART * KTOP;
  for (int t = 0; t < NPART * KTOP; ++t) top9_insert(kv, ki, pv[t], pi[t]);
#pragma unroll
  for (int t = 0; t < KTOP; ++t) {
    kval[(size_t)i * KTOP + t] = kv[t];
    kidx[(size_t)i * KTOP + t] = ki[t];
  }
}

// ---------------------------------------------------------------------------
// k3: mutual mask + softmax over <=9 entries + adapted query + normalize +
// project on normalized prototypes, scale by tao. One wave per query row.
__global__ void k3_out(const float* __restrict__ x, const float* __restrict__ kval,
                       const int* __restrict__ kidx, const float* __restrict__ protnT,
                       const float* __restrict__ taop, float* __restrict__ out) {
  __shared__ float sw[4][KTOP];
  __shared__ int   sj[4][KTOP];
  __shared__ float an[4][D];
  int lane = threadIdx.x & 63;
  int wv   = threadIdx.x >> 6;
  int i = blockIdx.x * 4 + wv;

  float v = -INFINITY; int jt = 0; bool mut = false;
  if (lane < KTOP) {
    v  = kval[(size_t)i * KTOP + lane];
    jt = kidx[(size_t)i * KTOP + lane];
    const int* oj = kidx + (size_t)jt * KTOP;
#pragma unroll
    for (int t = 0; t < KTOP; ++t) mut = mut || (oj[t] == i);
  }
  float lv = mut ? v : -INFINITY;
#pragma unroll
  for (int off = 1; off < 16; off <<= 1) lv = fmaxf(lv, __shfl_xor(lv, off));
  float wexp = mut ? expf(v - lv) : 0.f;    // self is always mutual -> z >= 1
  float z = wexp;
#pragma unroll
  for (int off = 1; off < 16; off <<= 1) z += __shfl_xor(z, off);
  if (lane < KTOP) { sw[wv][lane] = wexp / z; sj[wv][lane] = jt; }
  __syncthreads();

  // adapted[i] = sum_t w_t * query[j_t]; lane owns dims lane and lane+64
  float a0 = 0.f, a1 = 0.f;
#pragma unroll
  for (int t = 0; t < KTOP; ++t) {
    float wt = sw[wv][t];
    if (wt != 0.f) {
      int j = sj[wv][t];
      int xr = (j >> 7) * XROW + KSHOT + (j & 127);
      const float* qr = x + (size_t)xr * D;
      a0 += wt * qr[lane];
      a1 += wt * qr[64 + lane];
    }
  }
  float ss = a0 * a0 + a1 * a1;
#pragma unroll
  for (int off = 1; off < 64; off <<= 1) ss += __shfl_xor(ss, off);
  float rn = 1.0f / fmaxf(sqrtf(ss), EPSV);
  an[wv][lane]      = a0 * rn;
  an[wv][64 + lane] = a1 * rn;
  __syncthreads();

  // out[i][c] = tao * <an, protn[c]> ; lane = class c, protnT coalesced
  float acc = 0.f;
#pragma unroll 8
  for (int d = 0; d < D; ++d) acc += an[wv][d] * protnT[d * NCLS + lane];
  out[(size_t)i * NCLS + lane] = taop[0] * acc;
}

// ---------------------------------------------------------------------------
extern "C" void kernel_launch(void* const* d_in, const int* in_sizes, int n_in,
                              void* d_out, int out_size, void* d_ws, size_t ws_size,
                              hipStream_t stream) {
  const float* x   = (const float*)d_in[0];
  const float* tao = (const float*)d_in[1];
  float* out = (float*)d_out;

  // workspace layout (floats), total ~23.7 MB
  float* qn     = (float*)d_ws;                       // 8192*128
  float* pkv    = qn + (size_t)M * D;                 // 8192*32*9
  int*   pki    = (int*)(pkv + (size_t)M * NPART * KTOP);
  float* kval   = (float*)(pki + (size_t)M * NPART * KTOP);  // 8192*9
  int*   kidx   = (int*)(kval + (size_t)M * KTOP);
  float* protnT = (float*)(kidx + (size_t)M * KTOP);  // 128*64

  k0_proto<<<NCLS, 64, 0, stream>>>(x, protnT);
  k1_qnorm<<<M / 4, 256, 0, stream>>>(x, qn);
  k2_topk<<<(M / IB) * SJ, TPB2, 0, stream>>>(qn, pkv, pki);
  k_merge<<<M / 256, 256, 0, stream>>>(pkv, pki, kval, kidx);
  k3_out<<<M / 4, 256, 0, stream>>>(x, kval, kidx, protnT, tao, out);
}